// Round 1
// baseline (288.770 us; speedup 1.0000x reference)
//
#include <hip/hip_runtime.h>

#define NB 8      // batches
#define NT 16     // timesteps
#define NN 256    // points
#define NS 3      // scales

// ---------------------------------------------------------------------------
// Kernel 1: leader-clustering group assignment on last-timestep distances.
// One block per batch, 256 threads (thread j owns point j).
// Sequential over pivot i; parallel over j. assigned[i] is only READ at
// iteration i and only WRITTEN (by thread i) at an earlier iteration, so a
// single barrier at the end of each iteration is sufficient. Leaders never
// set their own flag (it is never needed afterwards).
// ---------------------------------------------------------------------------
__global__ __launch_bounds__(NN) void groups_kernel(
    const float* __restrict__ positions,
    float* __restrict__ out_groups_f,   // float-encoded group ids in d_out
    int* __restrict__ out_groups_i)     // int group ids in workspace
{
    __shared__ float px[NN], py[NN];
    __shared__ unsigned int assigned[NN];
    __shared__ int grp[NN];

    const int b = blockIdx.x;
    const int j = threadIdx.x;

    // positions layout (B,T,N,2); last timestep t = NT-1
    const float2 p = ((const float2*)positions)[(b * NT + (NT - 1)) * NN + j];
    px[j] = p.x;
    py[j] = p.y;
    assigned[j] = 0u;
    grp[j] = 0;
    __syncthreads();

    int cur = 0;  // uniform across threads
    for (int i = 0; i < NN; ++i) {
        const bool is_new = (assigned[i] == 0u);
        if (is_new) {
            if (j > i) {
                if (assigned[j] == 0u) {
                    // bit-exact match to numpy: no fma contraction, exact sqrt
                    const float dx = px[i] - px[j];
                    const float dy = py[i] - py[j];
                    const float sq = __fadd_rn(__fmul_rn(dx, dx), __fmul_rn(dy, dy));
                    const float d  = (sq > 0.0f) ? __fsqrt_rn(sq) : 0.0f;
                    if (d <= 2.0f) {
                        grp[j] = cur;
                        assigned[j] = 1u;
                    }
                }
            } else if (j == i) {
                grp[j] = cur;  // leader: do NOT set assigned[i] (never read again)
            }
            ++cur;
        }
        // barrier + early exit: all points are either flagged or leaders
        const int done = __syncthreads_count((int)(assigned[j] != 0u));
        if (done + cur >= NN) break;
    }
    __syncthreads();

    out_groups_i[b * NN + j] = grp[j];
    out_groups_f[b * NN + j] = (float)grp[j];
}

// ---------------------------------------------------------------------------
// Kernel 2: adjacency + intra_adjacency. Grid = B*T*CHUNKS blocks; each block
// stages one (b,t)'s 256 points in LDS and writes ROWS rows of the 256x256
// pair matrix for all 3 scales (6 coalesced store streams).
// ---------------------------------------------------------------------------
#define CHUNKS 8
#define ROWS (NN / CHUNKS)  // 32

__global__ __launch_bounds__(NN) void adj_kernel(
    const float* __restrict__ positions,
    const float* __restrict__ displacements,
    const int* __restrict__ groups,
    float* __restrict__ adj,
    float* __restrict__ intra)
{
    __shared__ float px[NN], py[NN], ux[NN], uy[NN];
    __shared__ int grp[NN];

    const int blk = blockIdx.x;     // b*T*CHUNKS + t*CHUNKS + c
    const int c  = blk % CHUNKS;
    const int bt = blk / CHUNKS;
    const int t  = bt % NT;
    const int b  = bt / NT;
    const int j  = threadIdx.x;

    const float2 p = ((const float2*)positions)[(b * NT + t) * NN + j];
    const float2 u = ((const float2*)displacements)[(b * NT + t) * NN + j];
    px[j] = p.x;  py[j] = p.y;
    ux[j] = u.x;  uy[j] = u.y;
    grp[j] = groups[b * NN + j];
    __syncthreads();

    const int gj = grp[j];
    // adjacency flat index: (((b*3 + s)*T + t)*N + i)*N + j
    const size_t splane  = (size_t)NT * NN * NN;
    const size_t base_bt = ((size_t)(b * NS) * NT + t) * (size_t)(NN * NN);

    for (int r = 0; r < ROWS; ++r) {
        const int i = c * ROWS + r;

        const float dx = px[i] - px[j];
        const float dy = py[i] - py[j];
        const float sqd = __fadd_rn(__fmul_rn(dx, dx), __fmul_rn(dy, dy));
        const float d   = (sqd > 0.0f) ? __fsqrt_rn(sqd) : 0.0f;

        const float ex = ux[i] - ux[j];
        const float ey = uy[i] - uy[j];
        const float sqe = __fadd_rn(__fmul_rn(ex, ex), __fmul_rn(ey, ey));
        const float dn  = (sqe > 0.0f) ? __fsqrt_rn(sqe) : 0.0f;

        const float w  = 1.0f / (dn + 1e-6f);   // never inf (dn >= 0)
        const float gm = (grp[i] == gj) ? 1.0f : 0.0f;

        const float a0 = (d <= 0.5f) ? w : 0.0f;
        const float a1 = (d <= 1.0f) ? w : 0.0f;
        const float a2 = (d <= 2.0f) ? w : 0.0f;

        const size_t off = base_bt + (size_t)i * NN + j;
        adj[off]              = a0;
        adj[off + splane]     = a1;
        adj[off + 2 * splane] = a2;
        intra[off]              = a0 * gm;
        intra[off + splane]     = a1 * gm;
        intra[off + 2 * splane] = a2 * gm;
    }
}

extern "C" void kernel_launch(void* const* d_in, const int* in_sizes, int n_in,
                              void* d_out, int out_size, void* d_ws, size_t ws_size,
                              hipStream_t stream) {
    const float* positions     = (const float*)d_in[0];
    const float* displacements = (const float*)d_in[1];
    float* out = (float*)d_out;

    const size_t ADJ_ELEMS = (size_t)NB * NS * NT * NN * NN;  // 25,165,824
    float* adj      = out;
    float* groups_f = out + ADJ_ELEMS;
    float* intra    = out + ADJ_ELEMS + (size_t)NB * NN;
    int*   groups_i = (int*)d_ws;

    groups_kernel<<<NB, NN, 0, stream>>>(positions, groups_f, groups_i);
    adj_kernel<<<NB * NT * CHUNKS, NN, 0, stream>>>(positions, displacements,
                                                    groups_i, adj, intra);
}

// Round 4
// 229.516 us; speedup vs baseline: 1.2582x; 1.2582x over previous
//
#include <hip/hip_runtime.h>

#define NB 8      // batches
#define NT 16     // timesteps
#define NN 256    // points
#define NS 3      // scales

typedef float f32x4 __attribute__((ext_vector_type(4)));
typedef int   i32x4 __attribute__((ext_vector_type(4)));

// ---------------------------------------------------------------------------
// Kernel 1: leader-clustering groups, ONE WAVE per batch, zero barriers.
// Lane l owns points j = k*64 + l (k=0..3). assigned = 4x u64 masks kept
// uniform via __ballot; pivot coords broadcast via __shfl. Distance math is
// bit-exact vs the numpy reference (no fma contraction, correctly-rounded
// sqrt) because group ids have zero error tolerance.
// ---------------------------------------------------------------------------
__global__ __launch_bounds__(64) void groups_kernel(
    const float* __restrict__ positions,
    float* __restrict__ out_groups_f,   // float-encoded ids in d_out
    int* __restrict__ out_groups_i)     // int ids in workspace
{
    const int b    = blockIdx.x;
    const int lane = threadIdx.x;   // 0..63

    const float2* __restrict__ P =
        ((const float2*)positions) + ((size_t)b * NT + (NT - 1)) * NN;

    float px[4], py[4];
#pragma unroll
    for (int k = 0; k < 4; ++k) {
        const float2 p = P[k * 64 + lane];
        px[k] = p.x; py[k] = p.y;
    }

    unsigned long long amask[4] = {0ull, 0ull, 0ull, 0ull};  // uniform
    int grp[4] = {0, 0, 0, 0};
    int cur = 0;

#pragma unroll
    for (int ki = 0; ki < 4; ++ki) {
        for (int li = 0; li < 64; ++li) {
            if ((amask[ki] >> li) & 1ull) continue;   // pivot already assigned
            // pivot i = ki*64 + li is a new leader
            const float pix = __shfl(px[ki], li);
            const float piy = __shfl(py[ki], li);
#pragma unroll
            for (int k = ki; k < 4; ++k) {
                const bool elig = (k > ki) || (lane >= li);       // idx >= i
                const bool unas = (((amask[k] >> lane) & 1ull) == 0ull);
                const float dx = pix - px[k];
                const float dy = piy - py[k];
                const float sq = __fadd_rn(__fmul_rn(dx, dx), __fmul_rn(dy, dy));
                const float d  = (sq > 0.0f) ? __fsqrt_rn(sq) : 0.0f;
                const bool newly = elig && unas && (d <= 2.0f);
                const unsigned long long nb = __ballot(newly);
                amask[k] |= nb;                                   // uniform
                if (newly) grp[k] = cur;
            }
            ++cur;
            // all 256 points assigned (incl. the pivot itself) -> done
            if (!(~(amask[0] & amask[1] & amask[2] & amask[3]))) break;
        }
    }

#pragma unroll
    for (int k = 0; k < 4; ++k) {
        const int j = b * NN + k * 64 + lane;
        out_groups_i[j] = grp[k];
        out_groups_f[j] = (float)grp[k];
    }
}

// ---------------------------------------------------------------------------
// Kernel 2: adjacency + intra. Each thread owns 4 consecutive columns ->
// all global stores are dwordx4 (non-temporal; output is write-once).
// Column data hoisted to registers once per block; row data is wave-uniform
// LDS broadcast. Fast sqrt/rcp for the weight (tolerance ~2e4 >> 1ulp);
// exact sqrt for the position distance (indicator flip at a scale boundary
// would cost ~w ~ 1e6).
// ---------------------------------------------------------------------------
#define CHUNKS 8
#define ROWS (NN / CHUNKS)  // 32 rows per block

__global__ __launch_bounds__(NN) void adj_kernel(
    const float* __restrict__ positions,
    const float* __restrict__ displacements,
    const int* __restrict__ groups,
    float* __restrict__ adj,
    float* __restrict__ intra)
{
    __shared__ float px[NN], py[NN], ux[NN], uy[NN];
    __shared__ int grp[NN];

    const int blk = blockIdx.x;          // b*T*CHUNKS + t*CHUNKS + c
    const int c   = blk & 7;
    const int bt  = blk >> 3;
    const int t   = bt & 15;
    const int b   = bt >> 4;
    const int tid = threadIdx.x;

    {
        const float2 p = ((const float2*)positions)[((size_t)b * NT + t) * NN + tid];
        const float2 u = ((const float2*)displacements)[((size_t)b * NT + t) * NN + tid];
        px[tid] = p.x;  py[tid] = p.y;
        ux[tid] = u.x;  uy[tid] = u.y;
        grp[tid] = groups[b * NN + tid];
    }
    __syncthreads();

    const int cl = tid & 63;   // column-quad index: cols 4*cl .. 4*cl+3
    const int rw = tid >> 6;   // row offset within each 4-row slab (wave id)

    // column data -> registers (ds_read_b128 each; 2-way bank alias = free)
    const f32x4 pxj = ((const f32x4*)px)[cl];
    const f32x4 pyj = ((const f32x4*)py)[cl];
    const f32x4 uxj = ((const f32x4*)ux)[cl];
    const f32x4 uyj = ((const f32x4*)uy)[cl];
    const i32x4 gj  = ((const i32x4*)grp)[cl];

    const size_t splane  = (size_t)NT * NN * NN;
    const size_t base_bt = ((size_t)(b * NS) * NT + t) * (size_t)(NN * NN);

    for (int q = 0; q < ROWS / 4; ++q) {
        const int i = c * ROWS + q * 4 + rw;          // wave-uniform row
        const float pix = px[i], piy = py[i];
        const float uix = ux[i], uiy = uy[i];
        const int   gi  = grp[i];

        f32x4 A0, A1, A2, I0, I1, I2;

#pragma unroll
        for (int cc = 0; cc < 4; ++cc) {
            const float dx = pix - pxj[cc];
            const float dy = piy - pyj[cc];
            const float sq = __fadd_rn(__fmul_rn(dx, dx), __fmul_rn(dy, dy));
            const float d  = (sq > 0.0f) ? __fsqrt_rn(sq) : 0.0f;  // exact

            const float ex = uix - uxj[cc];
            const float ey = uiy - uyj[cc];
            const float sqe = __fadd_rn(__fmul_rn(ex, ex), __fmul_rn(ey, ey));
            const float dn  = __builtin_amdgcn_sqrtf(sqe);         // fast, sqrt(0)=0
            const float w   = __builtin_amdgcn_rcpf(dn + 1e-6f);   // fast rcp

            const float gm = (gi == gj[cc]) ? 1.0f : 0.0f;
            const float a0 = (d <= 0.5f) ? w : 0.0f;
            const float a1 = (d <= 1.0f) ? w : 0.0f;
            const float a2 = (d <= 2.0f) ? w : 0.0f;

            A0[cc] = a0;       A1[cc] = a1;       A2[cc] = a2;
            I0[cc] = a0 * gm;  I1[cc] = a1 * gm;  I2[cc] = a2 * gm;
        }

        const size_t off = base_bt + (size_t)i * NN + 4 * cl;
        __builtin_nontemporal_store(A0, (f32x4*)(adj + off));
        __builtin_nontemporal_store(A1, (f32x4*)(adj + off + splane));
        __builtin_nontemporal_store(A2, (f32x4*)(adj + off + 2 * splane));
        __builtin_nontemporal_store(I0, (f32x4*)(intra + off));
        __builtin_nontemporal_store(I1, (f32x4*)(intra + off + splane));
        __builtin_nontemporal_store(I2, (f32x4*)(intra + off + 2 * splane));
    }
}

extern "C" void kernel_launch(void* const* d_in, const int* in_sizes, int n_in,
                              void* d_out, int out_size, void* d_ws, size_t ws_size,
                              hipStream_t stream) {
    const float* positions     = (const float*)d_in[0];
    const float* displacements = (const float*)d_in[1];
    float* out = (float*)d_out;

    const size_t ADJ_ELEMS = (size_t)NB * NS * NT * NN * NN;  // 25,165,824
    float* adj      = out;
    float* groups_f = out + ADJ_ELEMS;
    float* intra    = out + ADJ_ELEMS + (size_t)NB * NN;
    int*   groups_i = (int*)d_ws;

    groups_kernel<<<NB, 64, 0, stream>>>(positions, groups_f, groups_i);
    adj_kernel<<<NB * NT * CHUNKS, NN, 0, stream>>>(positions, displacements,
                                                    groups_i, adj, intra);
}

// Round 5
// 218.501 us; speedup vs baseline: 1.3216x; 1.0504x over previous
//
#include <hip/hip_runtime.h>

#define NB 8      // batches
#define NT 16     // timesteps
#define NN 256    // points
#define NS 3      // scales

typedef float f32x4 __attribute__((ext_vector_type(4)));
typedef int   i32x4 __attribute__((ext_vector_type(4)));

// ---------------------------------------------------------------------------
// Kernel 1: leader-clustering groups, ONE WAVE per batch, zero barriers.
// Lane l owns points j = k*64 + l (k=0..3). assigned = 4x u64 masks kept
// uniform via __ballot; pivot coords broadcast via __shfl. Distance math is
// bit-exact vs the numpy reference (no fma contraction, correctly-rounded
// sqrt) because group ids have zero error tolerance.
// ---------------------------------------------------------------------------
__global__ __launch_bounds__(64) void groups_kernel(
    const float* __restrict__ positions,
    float* __restrict__ out_groups_f,   // float-encoded ids in d_out
    int* __restrict__ out_groups_i)     // int ids in workspace
{
    const int b    = blockIdx.x;
    const int lane = threadIdx.x;   // 0..63

    const float2* __restrict__ P =
        ((const float2*)positions) + ((size_t)b * NT + (NT - 1)) * NN;

    float px[4], py[4];
#pragma unroll
    for (int k = 0; k < 4; ++k) {
        const float2 p = P[k * 64 + lane];
        px[k] = p.x; py[k] = p.y;
    }

    unsigned long long amask[4] = {0ull, 0ull, 0ull, 0ull};  // uniform
    int grp[4] = {0, 0, 0, 0};
    int cur = 0;

#pragma unroll
    for (int ki = 0; ki < 4; ++ki) {
        for (int li = 0; li < 64; ++li) {
            if ((amask[ki] >> li) & 1ull) continue;   // pivot already assigned
            // pivot i = ki*64 + li is a new leader
            const float pix = __shfl(px[ki], li);
            const float piy = __shfl(py[ki], li);
#pragma unroll
            for (int k = ki; k < 4; ++k) {
                const bool elig = (k > ki) || (lane >= li);       // idx >= i
                const bool unas = (((amask[k] >> lane) & 1ull) == 0ull);
                const float dx = pix - px[k];
                const float dy = piy - py[k];
                const float sq = __fadd_rn(__fmul_rn(dx, dx), __fmul_rn(dy, dy));
                const float d  = (sq > 0.0f) ? __fsqrt_rn(sq) : 0.0f;
                const bool newly = elig && unas && (d <= 2.0f);
                const unsigned long long nb = __ballot(newly);
                amask[k] |= nb;                                   // uniform
                if (newly) grp[k] = cur;
            }
            ++cur;
            // all 256 points assigned (incl. the pivot itself) -> done
            if (!(~(amask[0] & amask[1] & amask[2] & amask[3]))) break;
        }
    }

#pragma unroll
    for (int k = 0; k < 4; ++k) {
        const int j = b * NN + k * 64 + lane;
        out_groups_i[j] = grp[k];
        out_groups_f[j] = (float)grp[k];
    }
}

// ---------------------------------------------------------------------------
// Kernel 2: adjacency + intra. Each thread owns 4 consecutive columns ->
// all global stores are dwordx4. Stores are PLAIN (write-back through L2):
// Round-4 evidence showed non-temporal stores ran at ~3.1 TB/s, half of the
// 6.4 TB/s the harness's fillBuffer achieves with normal write-back stores.
// Column data hoisted to registers once per block; row data is wave-uniform
// LDS broadcast. Fast sqrt/rcp for the weight (passed with absmax 0.0);
// exact sqrt for the position distance (indicator flip would cost ~w ~ 1e6).
// ---------------------------------------------------------------------------
#define CHUNKS 8
#define ROWS (NN / CHUNKS)  // 32 rows per block

__global__ __launch_bounds__(NN) void adj_kernel(
    const float* __restrict__ positions,
    const float* __restrict__ displacements,
    const int* __restrict__ groups,
    float* __restrict__ adj,
    float* __restrict__ intra)
{
    __shared__ float px[NN], py[NN], ux[NN], uy[NN];
    __shared__ int grp[NN];

    const int blk = blockIdx.x;          // b*T*CHUNKS + t*CHUNKS + c
    const int c   = blk & 7;
    const int bt  = blk >> 3;
    const int t   = bt & 15;
    const int b   = bt >> 4;
    const int tid = threadIdx.x;

    {
        const float2 p = ((const float2*)positions)[((size_t)b * NT + t) * NN + tid];
        const float2 u = ((const float2*)displacements)[((size_t)b * NT + t) * NN + tid];
        px[tid] = p.x;  py[tid] = p.y;
        ux[tid] = u.x;  uy[tid] = u.y;
        grp[tid] = groups[b * NN + tid];
    }
    __syncthreads();

    const int cl = tid & 63;   // column-quad index: cols 4*cl .. 4*cl+3
    const int rw = tid >> 6;   // row offset within each 4-row slab (wave id)

    // column data -> registers (ds_read_b128 each; 2-way bank alias = free)
    const f32x4 pxj = ((const f32x4*)px)[cl];
    const f32x4 pyj = ((const f32x4*)py)[cl];
    const f32x4 uxj = ((const f32x4*)ux)[cl];
    const f32x4 uyj = ((const f32x4*)uy)[cl];
    const i32x4 gj  = ((const i32x4*)grp)[cl];

    const size_t splane  = (size_t)NT * NN * NN;
    const size_t base_bt = ((size_t)(b * NS) * NT + t) * (size_t)(NN * NN);

    for (int q = 0; q < ROWS / 4; ++q) {
        const int i = c * ROWS + q * 4 + rw;          // wave-uniform row
        const float pix = px[i], piy = py[i];
        const float uix = ux[i], uiy = uy[i];
        const int   gi  = grp[i];

        f32x4 A0, A1, A2, I0, I1, I2;

#pragma unroll
        for (int cc = 0; cc < 4; ++cc) {
            const float dx = pix - pxj[cc];
            const float dy = piy - pyj[cc];
            const float sq = __fadd_rn(__fmul_rn(dx, dx), __fmul_rn(dy, dy));
            const float d  = (sq > 0.0f) ? __fsqrt_rn(sq) : 0.0f;  // exact

            const float ex = uix - uxj[cc];
            const float ey = uiy - uyj[cc];
            const float sqe = __fadd_rn(__fmul_rn(ex, ex), __fmul_rn(ey, ey));
            const float dn  = __builtin_amdgcn_sqrtf(sqe);         // fast, sqrt(0)=0
            const float w   = __builtin_amdgcn_rcpf(dn + 1e-6f);   // fast rcp

            const float gm = (gi == gj[cc]) ? 1.0f : 0.0f;
            const float a0 = (d <= 0.5f) ? w : 0.0f;
            const float a1 = (d <= 1.0f) ? w : 0.0f;
            const float a2 = (d <= 2.0f) ? w : 0.0f;

            A0[cc] = a0;       A1[cc] = a1;       A2[cc] = a2;
            I0[cc] = a0 * gm;  I1[cc] = a1 * gm;  I2[cc] = a2 * gm;
        }

        const size_t off = base_bt + (size_t)i * NN + 4 * cl;
        *(f32x4*)(adj + off)                = A0;
        *(f32x4*)(adj + off + splane)       = A1;
        *(f32x4*)(adj + off + 2 * splane)   = A2;
        *(f32x4*)(intra + off)              = I0;
        *(f32x4*)(intra + off + splane)     = I1;
        *(f32x4*)(intra + off + 2 * splane) = I2;
    }
}

extern "C" void kernel_launch(void* const* d_in, const int* in_sizes, int n_in,
                              void* d_out, int out_size, void* d_ws, size_t ws_size,
                              hipStream_t stream) {
    const float* positions     = (const float*)d_in[0];
    const float* displacements = (const float*)d_in[1];
    float* out = (float*)d_out;

    const size_t ADJ_ELEMS = (size_t)NB * NS * NT * NN * NN;  // 25,165,824
    float* adj      = out;
    float* groups_f = out + ADJ_ELEMS;
    float* intra    = out + ADJ_ELEMS + (size_t)NB * NN;
    int*   groups_i = (int*)d_ws;

    groups_kernel<<<NB, 64, 0, stream>>>(positions, groups_f, groups_i);
    adj_kernel<<<NB * NT * CHUNKS, NN, 0, stream>>>(positions, displacements,
                                                    groups_i, adj, intra);
}